// Round 16
// baseline (272.269 us; speedup 1.0000x reference)
//
#include <hip/hip_runtime.h>
#include <hip/hip_bf16.h>
#include <type_traits>

#define DEV __device__ __forceinline__

typedef __bf16 bf16x8 __attribute__((ext_vector_type(8)));
typedef float f32x4 __attribute__((ext_vector_type(4)));
typedef float f32x16 __attribute__((ext_vector_type(16)));
typedef unsigned short u16;
typedef unsigned int u32;

// ---------- helpers ----------
DEV u16 f32_to_bf16(float f) {                 // round-to-nearest-even
  union { float f; u32 u; } x; x.f = f;
  u32 r = (x.u + 0x7FFFu + ((x.u >> 16) & 1u)) >> 16;
  return (u16)r;
}

DEV u32 pack2(float a, float b) {              // v_cvt_pk_bf16_f32 path
  union { __hip_bfloat162 h; u32 u; } c;
  c.h = __float22bfloat162_rn(float2{a, b});
  return c.u;
}

// async global->LDS, 16B per lane. HW writes wave-uniform base + lane*16 (linear).
DEV void ld_lds16(const void* g, void* l) {
  __builtin_amdgcn_global_load_lds(
      (const __attribute__((address_space(1))) u32*)g,
      (__attribute__((address_space(3))) u32*)l, 16, 0, 0);
}

#define MFMA16(a, b, c) __builtin_amdgcn_mfma_f32_16x16x32_bf16(a, b, c, 0, 0, 0)
#define MFMA32(a, b, c) __builtin_amdgcn_mfma_f32_32x32x16_bf16(a, b, c, 0, 0, 0)

// ---------- fused cast f32 -> bf16 for all five inputs ----------
__global__ __launch_bounds__(256) void cast_all(
    const float* __restrict__ x,  const float* __restrict__ wq,
    const float* __restrict__ wk, const float* __restrict__ wv,
    const float* __restrict__ wo,
    u16* __restrict__ xb,  u16* __restrict__ wqb, u16* __restrict__ wkb,
    u16* __restrict__ wvb, u16* __restrict__ wob) {
  int bid = blockIdx.x;
  const float* src; u16* dst; int base;
  if (bid < 8192)       { src = x;  dst = xb;  base = bid; }
  else if (bid < 12288) { src = wq; dst = wqb; base = bid - 8192; }
  else if (bid < 16384) { src = wk; dst = wkb; base = bid - 12288; }
  else if (bid < 20480) { src = wv; dst = wvb; base = bid - 16384; }
  else                  { src = wo; dst = wob; base = bid - 20480; }
  int i = (base * 256 + threadIdx.x) * 4;
  float4 v = *reinterpret_cast<const float4*>(src + i);
  ushort4 o;
  o.x = f32_to_bf16(v.x); o.y = f32_to_bf16(v.y);
  o.z = f32_to_bf16(v.z); o.w = f32_to_bf16(v.w);
  *reinterpret_cast<ushort4*>(dst + i) = o;
}

// ---------- GEMM 256x256, counted-vmcnt pipeline: C = A * B^T * osc ---------
// 8 waves (2M x 4N), 32x32x16 MFMA, 2-buf LDS (128 KiB). Tile t+1's 8 loads
// are issued at the top of tile t and stay IN FLIGHT across the barriers
// (s_waitcnt vmcnt(8), never 0 in the main loop). Raw s_barrier pair per
// K-tile; lgkmcnt-pinned 16-MFMA clusters. Dual output: cols >= nsplit go to
// C2 (col - nsplit), scaled oscHi; else C, oscLo.
template <typename OutT>
__global__ __launch_bounds__(512, 2) void gemm_nt256(
    const u16* __restrict__ A, const u16* __restrict__ B,
    OutT* __restrict__ C, OutT* __restrict__ C2,
    int M, int N, int K, int ldc,
    float oscLo, float oscHi, int nsplit, int nbx) {
  __shared__ __align__(16) u16 sA[2][256 * 64];
  __shared__ __align__(16) u16 sB[2][256 * 64];
  const int tid = threadIdx.x;
  const int lane = tid & 63, wid = tid >> 6;
  const int l31 = lane & 31, hi5 = lane >> 5;
  const int wm = wid >> 2, wn = wid & 3;
  // bijective XCD swizzle (gridDim.x % 8 == 0)
  const int cpx = gridDim.x >> 3;
  const int swz = ((int)blockIdx.x & 7) * cpx + ((int)blockIdx.x >> 3);
  const int m0 = (swz / nbx) * 256, n0 = (swz % nbx) * 256;
  const int NT = K >> 6;

  f32x16 acc[4][2] = {};  // [m-frag 32][n-frag 32]

  auto stage = [&](int buf, int t) {
    const int k0 = t << 6;
#pragma unroll
    for (int i = 0; i < 4; ++i) {
      int e = i * 512 + tid;                       // 2048 x 16B chunks
      int r = e >> 3;                              // 8 chunks per 128B row
      int bc = ((e & 7) * 16) ^ ((r & 7) << 4);    // inverse-swizzled source
      ld_lds16(A + (size_t)(m0 + r) * K + k0 + (bc >> 1), &sA[buf][e * 8]);
    }
#pragma unroll
    for (int i = 0; i < 4; ++i) {
      int e = i * 512 + tid;
      int r = e >> 3;
      int bc = ((e & 7) * 16) ^ ((r & 7) << 4);
      ld_lds16(B + (size_t)(n0 + r) * K + k0 + (bc >> 1), &sB[buf][e * 8]);
    }
  };

  stage(0, 0);

  for (int t = 0; t < NT; ++t) {
    const u16* cA = sA[t & 1];
    const u16* cB = sB[t & 1];
    if (t + 1 < NT) {
      stage((t + 1) & 1, t + 1);   // 8 loads issued; stay in flight past bar
      asm volatile("s_waitcnt vmcnt(8)" ::: "memory");   // drain tile t only
    } else {
      asm volatile("s_waitcnt vmcnt(0)" ::: "memory");   // last tile: drain all
    }
    __builtin_amdgcn_s_barrier();          // tile t visible to all waves
    __builtin_amdgcn_sched_barrier(0);

#pragma unroll
    for (int kh = 0; kh < 2; ++kh) {       // kc-split phases: {0,1}, {2,3}
      bf16x8 afr[4][2], bfr[2][2];
#pragma unroll
      for (int mi = 0; mi < 4; ++mi)
#pragma unroll
        for (int kc = 0; kc < 2; ++kc) {
          int row = wm * 128 + mi * 32 + l31;
          int bo = (((kh * 2 + kc) * 32 + hi5 * 16)) ^ ((row & 7) << 4);
          afr[mi][kc] = *(const bf16x8*)((const char*)cA + row * 128 + bo);
        }
#pragma unroll
      for (int ni = 0; ni < 2; ++ni)
#pragma unroll
        for (int kc = 0; kc < 2; ++kc) {
          int row = wn * 64 + ni * 32 + l31;
          int bo = (((kh * 2 + kc) * 32 + hi5 * 16)) ^ ((row & 7) << 4);
          bfr[ni][kc] = *(const bf16x8*)((const char*)cB + row * 128 + bo);
        }
      asm volatile("s_waitcnt lgkmcnt(0)" ::: "memory");
      __builtin_amdgcn_sched_barrier(0);
      __builtin_amdgcn_s_setprio(1);
#pragma unroll
      for (int mi = 0; mi < 4; ++mi)
#pragma unroll
        for (int ni = 0; ni < 2; ++ni)
#pragma unroll
          for (int kc = 0; kc < 2; ++kc)
            acc[mi][ni] = MFMA32(afr[mi][kc], bfr[ni][kc], acc[mi][ni]);
      __builtin_amdgcn_s_setprio(0);
      __builtin_amdgcn_sched_barrier(0);
    }
    __builtin_amdgcn_s_barrier();          // all reads of buf t done -> reusable
    __builtin_amdgcn_sched_barrier(0);
  }

  // epilogue: C/D 32x32 layout col=l31, row=(j&3)+8*(j>>2)+4*hi5
#pragma unroll
  for (int mi = 0; mi < 4; ++mi)
#pragma unroll
    for (int ni = 0; ni < 2; ++ni) {
      int colb = n0 + wn * 64 + ni * 32;
      bool lo_side = (colb < nsplit);
      OutT* dst = lo_side ? C : C2;
      float osc = lo_side ? oscLo : oscHi;
      int col = (lo_side ? colb : colb - nsplit) + l31;
#pragma unroll
      for (int j = 0; j < 16; ++j) {
        size_t row = m0 + wm * 128 + mi * 32 + (j & 3) + 8 * (j >> 2) + 4 * hi5;
        float v = acc[mi][ni][j] * osc;
        if constexpr (std::is_same<OutT, float>::value)
          dst[row * ldc + col] = v;
        else
          dst[row * ldc + col] = f32_to_bf16(v);
      }
    }
}

// ---------- GEMM 128x128 (m97-style, proven): C = A * B^T * osc -------------
template <typename OutT>
__global__ __launch_bounds__(256) void gemm_nt(const u16* __restrict__ A,
                                               const u16* __restrict__ B,
                                               OutT* __restrict__ C,
                                               int M, int N, int K, float osc) {
  __shared__ __align__(16) u16 sA[128 * 64];
  __shared__ __align__(16) u16 sB[128 * 64];
  const int tid = threadIdx.x;
  const int lane = tid & 63, wid = tid >> 6;
  const int lo = lane & 15, hi = lane >> 4;
  const int wm = wid >> 1, wn = wid & 1;
  const int m0 = blockIdx.y * 128, n0 = blockIdx.x * 128;

  f32x4 acc[4][4] = {};

  for (int k0 = 0; k0 < K; k0 += 64) {
    __syncthreads();
#pragma unroll
    for (int i = 0; i < 4; ++i) {
      int e16 = i * 256 + tid;
      int r = e16 >> 3;
      int bcol = ((e16 & 7) * 16) ^ ((r & 7) << 4);
      int col = bcol >> 1;
      ld_lds16(A + (size_t)(m0 + r) * K + k0 + col, sA + e16 * 8);
      ld_lds16(B + (size_t)(n0 + r) * K + k0 + col, sB + e16 * 8);
    }
    __syncthreads();
#pragma unroll
    for (int kc = 0; kc < 2; ++kc) {
      bf16x8 a[4], b[4];
#pragma unroll
      for (int i = 0; i < 4; ++i) {
        int row = wm * 64 + i * 16 + lo;
        int boff = ((kc * 32 + hi * 8) * 2) ^ ((row & 7) << 4);
        a[i] = *(const bf16x8*)((const char*)sA + row * 128 + boff);
      }
#pragma unroll
      for (int i = 0; i < 4; ++i) {
        int row = wn * 64 + i * 16 + lo;
        int boff = ((kc * 32 + hi * 8) * 2) ^ ((row & 7) << 4);
        b[i] = *(const bf16x8*)((const char*)sB + row * 128 + boff);
      }
#pragma unroll
      for (int mi = 0; mi < 4; ++mi)
#pragma unroll
        for (int ni = 0; ni < 4; ++ni)
          acc[mi][ni] = MFMA16(a[mi], b[ni], acc[mi][ni]);
    }
  }
#pragma unroll
  for (int mi = 0; mi < 4; ++mi)
#pragma unroll
    for (int r = 0; r < 4; ++r) {
      size_t row = m0 + wm * 64 + mi * 16 + hi * 4 + r;
#pragma unroll
      for (int ni = 0; ni < 4; ++ni) {
        int col = n0 + wn * 64 + ni * 16 + lo;
        float v = acc[mi][ni][r] * osc;
        if constexpr (std::is_same<OutT, float>::value)
          C[row * N + col] = v;
        else
          C[row * N + col] = f32_to_bf16(v);
      }
    }
}

// ---------- causal flash attention (XCD-pinned + LPT ordering) --------------
// Q,K: [tok 4096][feat 2048]; VT: [feat 2048][tok 4096].
// Linear grid of 512 blocks; all 16 q-tile blocks of one (b,h) group are
// placed at linear IDs == g (mod 8) -> one XCD (round-robin dispatch), so
// the group's 512 KB K/V stream stays L2-resident (FETCH 110->25 MB, R15).
// Within each XCD, blocks are ordered HEAVY-FIRST (qt descending = LPT):
// the 32-iter diagonal blocks start first, light blocks backfill -> no tail.
constexpr float RTHR2 = 11.5416f;   // defer-max threshold, log2 units (= 8 nats)

__global__ __launch_bounds__(256, 2) void attn_fwd(const u16* __restrict__ Q,
                                                   const u16* __restrict__ K,
                                                   const u16* __restrict__ VT,
                                                   u16* __restrict__ O) {
  __shared__ __align__(16) u16 sK[2][64 * 128];   // [kv 64][dh 128], swizzled
  __shared__ __align__(16) u16 sV[2][128 * 64];   // [dh 128][kv 64], swizzled

  // decode: lin = g%8 + 8*((g/8)*16 + (15-qt)), g = h + 16*b  (LPT: qt desc)
  const int lin = blockIdx.x;
  const int k8 = lin >> 3;
  const int qt = 15 - (k8 & 15);                   // heavy-first within XCD
  const int g  = ((k8 >> 4) << 3) | (lin & 7);     // group 0..31
  const int h = g & 15, b = g >> 4;

  const int tid = threadIdx.x;
  const int lane = tid & 63, wid = tid >> 6;
  const int l31 = lane & 31, hi5 = lane >> 5;

  const size_t baseQK = ((size_t)b * 2048) * 2048 + (size_t)h * 128;
  const size_t baseV  = ((size_t)h * 128) * 4096 + (size_t)b * 2048;
  const int q0 = qt * 128;
  const int qw = q0 + wid * 32;      // wave's first query row
  const int qg = qw + l31;           // this lane's query row
  const int nt = 2 * qt + 2;

  // Q B-fragments (pre-scaled by SM_SCALE*log2e in the Q GEMM)
  bf16x8 qf[8];
#pragma unroll
  for (int kc = 0; kc < 8; ++kc)
    qf[kc] = *(const bf16x8*)(Q + baseQK + (size_t)qg * 2048 + kc * 16 + hi5 * 8);

  f32x16 o[4] = {};                  // O^T: [dh block d*32 + rowpat][q=l31]
  float m = -INFINITY, ls = 0.f;

  auto stage = [&](int buf, int t) {
    const int kv = t * 64;
#pragma unroll
    for (int i = 0; i < 4; ++i) {    // K tile: 64 rows x 256B
      int e = i * 256 + tid;
      int r = e >> 4;
      int bc = ((e & 15) * 16) ^ ((r & 7) << 4);
      ld_lds16(K + baseQK + (size_t)(kv + r) * 2048 + (bc >> 1), &sK[buf][e * 8]);
    }
#pragma unroll
    for (int i = 0; i < 4; ++i) {    // VT tile: 128 rows x 128B
      int e = i * 256 + tid;
      int r = e >> 3;
      int bc = ((e & 7) * 16) ^ ((r & 7) << 4);
      ld_lds16(VT + baseV + (size_t)r * 4096 + kv + (bc >> 1), &sV[buf][e * 8]);
    }
  };

  stage(0, 0);

  for (int t = 0; t < nt; ++t) {
    __syncthreads();                 // stage(t) complete; prev readers done
    if (t + 1 < nt) stage((t + 1) & 1, t + 1);
    const int kv0 = t * 64;
    if (kv0 > qw + 31) continue;     // beyond this wave's causal range
    const u16* bK = sK[t & 1];
    const u16* bV = sV[t & 1];

    // ---- S = K * Q^T : lane holds S[key(j,hi5)+kb*32][q=l31] ----
    f32x16 s[2] = {};
#pragma unroll
    for (int kb = 0; kb < 2; ++kb) {
      int row = kb * 32 + l31;
      int rsw = (row & 7) << 4;
#pragma unroll
      for (int kc = 0; kc < 8; ++kc) {
        int bo = (kc * 32 + hi5 * 16) ^ rsw;
        bf16x8 kf = *(const bf16x8*)((const char*)bK + row * 256 + bo);
        s[kb] = MFMA32(kf, qf[kc], s[kb]);
      }
    }

    // ---- mask (diag tiles only) ----
    if (kv0 + 63 > qw) {
#pragma unroll
      for (int kb = 0; kb < 2; ++kb)
#pragma unroll
        for (int j = 0; j < 16; ++j) {
          int keyg = kv0 + kb * 32 + (j & 3) + 8 * (j >> 2) + 4 * hi5;
          s[kb][j] = (keyg > qg) ? -3e38f : s[kb][j];
        }
    }

    // ---- row max: in-lane + cross-half shfl ----
    float pmax = -3e38f;
#pragma unroll
    for (int kb = 0; kb < 2; ++kb)
#pragma unroll
      for (int j = 0; j < 16; ++j) pmax = fmaxf(pmax, s[kb][j]);
    pmax = fmaxf(pmax, __shfl_xor(pmax, 32));

    // ---- defer-max rescale (log2 units) ----
    if (!__all(pmax - m <= RTHR2)) {
      float mn = fmaxf(m, pmax);
      float fr = exp2f(m - mn);
      ls *= fr;
#pragma unroll
      for (int d = 0; d < 4; ++d) o[d] *= fr;
      m = mn;
    }

    // ---- exp2 + row sum ----
    float rs = 0.f;
#pragma unroll
    for (int kb = 0; kb < 2; ++kb)
#pragma unroll
      for (int j = 0; j < 16; ++j) {
        float pv = exp2f(s[kb][j] - m);
        s[kb][j] = pv;
        rs += pv;
      }
    rs += __shfl_xor(rs, 32);
    ls += rs;

    // ---- pack P to bf16 pairs, redistribute into PV B-frags ----
    union PF { u32 w[4]; bf16x8 v; };
    PF pf[4];
#pragma unroll
    for (int kb = 0; kb < 2; ++kb)
#pragma unroll
      for (int gp = 0; gp < 2; ++gp) {
        u32 keep[2], send[2];
#pragma unroll
        for (int w = 0; w < 2; ++w) {
          int ja = 8 * gp + 2 * w;
          int jb = 8 * gp + 4 + 2 * w;
          u32 aa = pack2(s[kb][ja], s[kb][ja + 1]);
          u32 bb = pack2(s[kb][jb], s[kb][jb + 1]);
          keep[w] = hi5 ? bb : aa;
          send[w] = hi5 ? aa : bb;
        }
        u32 recv0 = (u32)__shfl_xor((int)send[0], 32);
        u32 recv1 = (u32)__shfl_xor((int)send[1], 32);
        PF& f = pf[2 * kb + gp];
        f.w[0] = hi5 ? recv0 : keep[0];
        f.w[1] = hi5 ? recv1 : keep[1];
        f.w[2] = hi5 ? keep[0] : recv0;
        f.w[3] = hi5 ? keep[1] : recv1;
      }

    // ---- O^T += V^T * P ----
#pragma unroll
    for (int d = 0; d < 4; ++d) {
      int row = d * 32 + l31;
      int rsw = (row & 7) << 4;
#pragma unroll
      for (int ks = 0; ks < 4; ++ks) {
        int bo = (ks * 32 + hi5 * 16) ^ rsw;
        bf16x8 vf = *(const bf16x8*)((const char*)bV + row * 128 + bo);
        o[d] = MFMA32(vf, pf[ks].v, o[d]);
      }
    }
  }

  // ---- normalize + store: O[tok][feat] ----
  float inv = 1.f / ls;
  size_t orow = (size_t)b * 2048 + qg;
#pragma unroll
  for (int d = 0; d < 4; ++d)
#pragma unroll
    for (int G = 0; G < 4; ++G) {
      union { u32 u[2]; ushort4 s4; } st;
      st.u[0] = pack2(o[d][4 * G + 0] * inv, o[d][4 * G + 1] * inv);
      st.u[1] = pack2(o[d][4 * G + 2] * inv, o[d][4 * G + 3] * inv);
      int col = h * 128 + d * 32 + 8 * G + 4 * hi5;
      *(ushort4*)(O + orow * 2048 + col) = st.s4;
    }
}

// ---------- launch ----------
extern "C" void kernel_launch(void* const* d_in, const int* in_sizes, int n_in,
                              void* d_out, int out_size, void* d_ws, size_t ws_size,
                              hipStream_t stream) {
  const float* x  = (const float*)d_in[0];
  const float* Wq = (const float*)d_in[1];
  const float* Wk = (const float*)d_in[2];
  const float* Wv = (const float*)d_in[3];
  const float* Wo = (const float*)d_in[4];
  float* out = (float*)d_out;

  constexpr int B = 2, S = 2048, D = 2048;
  constexpr int M = B * S;  // 4096
  // SM_SCALE * log2(e) — folded into the Q projection epilogue
  constexpr float QSC = 0.12751742f;

  char* ws = (char*)d_ws;
  u16* xb  = (u16*)ws; ws += (size_t)M * D * 2;
  u16* wqb = (u16*)ws; ws += (size_t)D * D * 2;   // wqb||wkb contiguous ->
  u16* wkb = (u16*)ws; ws += (size_t)D * D * 2;   // fused [4096][2048] B matrix
  u16* wvb = (u16*)ws; ws += (size_t)D * D * 2;
  u16* wob = (u16*)ws; ws += (size_t)D * D * 2;
  u16* q   = (u16*)ws; ws += (size_t)M * D * 2;   // [tok 4096][2048]
  u16* k   = (u16*)ws; ws += (size_t)M * D * 2;   // [tok 4096][2048]
  u16* vT  = (u16*)ws; ws += (size_t)M * D * 2;   // [feat 2048][tok 4096]
  u16* att = (u16*)ws; ws += (size_t)M * D * 2;

  cast_all<<<24576, 256, 0, stream>>>(x, Wq, Wk, Wv, Wo, xb, wqb, wkb, wvb, wob);

  // fused Q|K projection (de-fused outputs): cols<2048 -> q (scaled), else -> k
  gemm_nt256<u16><<<256, 512, 0, stream>>>(xb, wqb, q, k, M, 2 * D, D, D,
                                           QSC, 1.0f, D, 16);
  // V^T = Wv * x^T : output [feature][token] — free transpose for attention
  gemm_nt<u16><<<dim3(M / 128, D / 128), 256, 0, stream>>>(wvb, xb, vT, D, M, D, 1.0f);

  // XCD-pinned linear grid (512 blocks), heavy-first (LPT) within each XCD
  attn_fwd<<<512, 256, 0, stream>>>(q, k, vT, att);

  gemm_nt<float><<<dim3(16, 32), 256, 0, stream>>>(att, wob, out, M, D, D, 1.0f);
}

// Round 17
// 255.632 us; speedup vs baseline: 1.0651x; 1.0651x over previous
//
#include <hip/hip_runtime.h>
#include <hip/hip_bf16.h>
#include <type_traits>

#define DEV __device__ __forceinline__

typedef __bf16 bf16x8 __attribute__((ext_vector_type(8)));
typedef float f32x4 __attribute__((ext_vector_type(4)));
typedef float f32x16 __attribute__((ext_vector_type(16)));
typedef unsigned short u16;
typedef unsigned int u32;

// ---------- helpers ----------
DEV u16 f32_to_bf16(float f) {                 // round-to-nearest-even
  union { float f; u32 u; } x; x.f = f;
  u32 r = (x.u + 0x7FFFu + ((x.u >> 16) & 1u)) >> 16;
  return (u16)r;
}

DEV u32 pack2(float a, float b) {              // v_cvt_pk_bf16_f32 path
  union { __hip_bfloat162 h; u32 u; } c;
  c.h = __float22bfloat162_rn(float2{a, b});
  return c.u;
}

// async global->LDS, 16B per lane. HW writes wave-uniform base + lane*16 (linear).
DEV void ld_lds16(const void* g, void* l) {
  __builtin_amdgcn_global_load_lds(
      (const __attribute__((address_space(1))) u32*)g,
      (__attribute__((address_space(3))) u32*)l, 16, 0, 0);
}

#define MFMA16(a, b, c) __builtin_amdgcn_mfma_f32_16x16x32_bf16(a, b, c, 0, 0, 0)
#define MFMA32(a, b, c) __builtin_amdgcn_mfma_f32_32x32x16_bf16(a, b, c, 0, 0, 0)

// ---------- fused cast f32 -> bf16 for all five inputs ----------
__global__ __launch_bounds__(256) void cast_all(
    const float* __restrict__ x,  const float* __restrict__ wq,
    const float* __restrict__ wk, const float* __restrict__ wv,
    const float* __restrict__ wo,
    u16* __restrict__ xb,  u16* __restrict__ wqb, u16* __restrict__ wkb,
    u16* __restrict__ wvb, u16* __restrict__ wob) {
  int bid = blockIdx.x;
  const float* src; u16* dst; int base;
  if (bid < 8192)       { src = x;  dst = xb;  base = bid; }
  else if (bid < 12288) { src = wq; dst = wqb; base = bid - 8192; }
  else if (bid < 16384) { src = wk; dst = wkb; base = bid - 12288; }
  else if (bid < 20480) { src = wv; dst = wvb; base = bid - 16384; }
  else                  { src = wo; dst = wob; base = bid - 20480; }
  int i = (base * 256 + threadIdx.x) * 4;
  float4 v = *reinterpret_cast<const float4*>(src + i);
  ushort4 o;
  o.x = f32_to_bf16(v.x); o.y = f32_to_bf16(v.y);
  o.z = f32_to_bf16(v.z); o.w = f32_to_bf16(v.w);
  *reinterpret_cast<ushort4*>(dst + i) = o;
}

// ---------- GEMM 256x256, counted-vmcnt pipeline: C = A * B^T * osc ---------
// 8 waves (2M x 4N), 32x32x16 MFMA, 2-buf LDS (128 KiB). Tile t+1's 8 loads
// are issued at the top of tile t and stay IN FLIGHT across the barriers
// (s_waitcnt vmcnt(8), never 0 in the main loop). Raw s_barrier pair per
// K-tile; lgkmcnt-pinned 16-MFMA clusters. Dual output: cols >= nsplit go to
// C2 (col - nsplit), scaled oscHi; else C, oscLo.
template <typename OutT>
__global__ __launch_bounds__(512, 2) void gemm_nt256(
    const u16* __restrict__ A, const u16* __restrict__ B,
    OutT* __restrict__ C, OutT* __restrict__ C2,
    int M, int N, int K, int ldc,
    float oscLo, float oscHi, int nsplit, int nbx) {
  __shared__ __align__(16) u16 sA[2][256 * 64];
  __shared__ __align__(16) u16 sB[2][256 * 64];
  const int tid = threadIdx.x;
  const int lane = tid & 63, wid = tid >> 6;
  const int l31 = lane & 31, hi5 = lane >> 5;
  const int wm = wid >> 2, wn = wid & 3;
  // bijective XCD swizzle (gridDim.x % 8 == 0)
  const int cpx = gridDim.x >> 3;
  const int swz = ((int)blockIdx.x & 7) * cpx + ((int)blockIdx.x >> 3);
  const int m0 = (swz / nbx) * 256, n0 = (swz % nbx) * 256;
  const int NT = K >> 6;

  f32x16 acc[4][2] = {};  // [m-frag 32][n-frag 32]

  auto stage = [&](int buf, int t) {
    const int k0 = t << 6;
#pragma unroll
    for (int i = 0; i < 4; ++i) {
      int e = i * 512 + tid;                       // 2048 x 16B chunks
      int r = e >> 3;                              // 8 chunks per 128B row
      int bc = ((e & 7) * 16) ^ ((r & 7) << 4);    // inverse-swizzled source
      ld_lds16(A + (size_t)(m0 + r) * K + k0 + (bc >> 1), &sA[buf][e * 8]);
    }
#pragma unroll
    for (int i = 0; i < 4; ++i) {
      int e = i * 512 + tid;
      int r = e >> 3;
      int bc = ((e & 7) * 16) ^ ((r & 7) << 4);
      ld_lds16(B + (size_t)(n0 + r) * K + k0 + (bc >> 1), &sB[buf][e * 8]);
    }
  };

  stage(0, 0);

  for (int t = 0; t < NT; ++t) {
    const u16* cA = sA[t & 1];
    const u16* cB = sB[t & 1];
    if (t + 1 < NT) {
      stage((t + 1) & 1, t + 1);   // 8 loads issued; stay in flight past bar
      asm volatile("s_waitcnt vmcnt(8)" ::: "memory");   // drain tile t only
    } else {
      asm volatile("s_waitcnt vmcnt(0)" ::: "memory");   // last tile: drain all
    }
    __builtin_amdgcn_s_barrier();          // tile t visible to all waves
    __builtin_amdgcn_sched_barrier(0);

#pragma unroll
    for (int kh = 0; kh < 2; ++kh) {       // kc-split phases: {0,1}, {2,3}
      bf16x8 afr[4][2], bfr[2][2];
#pragma unroll
      for (int mi = 0; mi < 4; ++mi)
#pragma unroll
        for (int kc = 0; kc < 2; ++kc) {
          int row = wm * 128 + mi * 32 + l31;
          int bo = (((kh * 2 + kc) * 32 + hi5 * 16)) ^ ((row & 7) << 4);
          afr[mi][kc] = *(const bf16x8*)((const char*)cA + row * 128 + bo);
        }
#pragma unroll
      for (int ni = 0; ni < 2; ++ni)
#pragma unroll
        for (int kc = 0; kc < 2; ++kc) {
          int row = wn * 64 + ni * 32 + l31;
          int bo = (((kh * 2 + kc) * 32 + hi5 * 16)) ^ ((row & 7) << 4);
          bfr[ni][kc] = *(const bf16x8*)((const char*)cB + row * 128 + bo);
        }
      asm volatile("s_waitcnt lgkmcnt(0)" ::: "memory");
      __builtin_amdgcn_sched_barrier(0);
      __builtin_amdgcn_s_setprio(1);
#pragma unroll
      for (int mi = 0; mi < 4; ++mi)
#pragma unroll
        for (int ni = 0; ni < 2; ++ni)
#pragma unroll
          for (int kc = 0; kc < 2; ++kc)
            acc[mi][ni] = MFMA32(afr[mi][kc], bfr[ni][kc], acc[mi][ni]);
      __builtin_amdgcn_s_setprio(0);
      __builtin_amdgcn_sched_barrier(0);
    }
    __builtin_amdgcn_s_barrier();          // all reads of buf t done -> reusable
    __builtin_amdgcn_sched_barrier(0);
  }

  // epilogue: C/D 32x32 layout col=l31, row=(j&3)+8*(j>>2)+4*hi5
#pragma unroll
  for (int mi = 0; mi < 4; ++mi)
#pragma unroll
    for (int ni = 0; ni < 2; ++ni) {
      int colb = n0 + wn * 64 + ni * 32;
      bool lo_side = (colb < nsplit);
      OutT* dst = lo_side ? C : C2;
      float osc = lo_side ? oscLo : oscHi;
      int col = (lo_side ? colb : colb - nsplit) + l31;
#pragma unroll
      for (int j = 0; j < 16; ++j) {
        size_t row = m0 + wm * 128 + mi * 32 + (j & 3) + 8 * (j >> 2) + 4 * hi5;
        float v = acc[mi][ni][j] * osc;
        if constexpr (std::is_same<OutT, float>::value)
          dst[row * ldc + col] = v;
        else
          dst[row * ldc + col] = f32_to_bf16(v);
      }
    }
}

// ---------- GEMM 128x128 (m97-style, proven): C = A * B^T * osc -------------
template <typename OutT>
__global__ __launch_bounds__(256) void gemm_nt(const u16* __restrict__ A,
                                               const u16* __restrict__ B,
                                               OutT* __restrict__ C,
                                               int M, int N, int K, float osc) {
  __shared__ __align__(16) u16 sA[128 * 64];
  __shared__ __align__(16) u16 sB[128 * 64];
  const int tid = threadIdx.x;
  const int lane = tid & 63, wid = tid >> 6;
  const int lo = lane & 15, hi = lane >> 4;
  const int wm = wid >> 1, wn = wid & 1;
  const int m0 = blockIdx.y * 128, n0 = blockIdx.x * 128;

  f32x4 acc[4][4] = {};

  for (int k0 = 0; k0 < K; k0 += 64) {
    __syncthreads();
#pragma unroll
    for (int i = 0; i < 4; ++i) {
      int e16 = i * 256 + tid;
      int r = e16 >> 3;
      int bcol = ((e16 & 7) * 16) ^ ((r & 7) << 4);
      int col = bcol >> 1;
      ld_lds16(A + (size_t)(m0 + r) * K + k0 + col, sA + e16 * 8);
      ld_lds16(B + (size_t)(n0 + r) * K + k0 + col, sB + e16 * 8);
    }
    __syncthreads();
#pragma unroll
    for (int kc = 0; kc < 2; ++kc) {
      bf16x8 a[4], b[4];
#pragma unroll
      for (int i = 0; i < 4; ++i) {
        int row = wm * 64 + i * 16 + lo;
        int boff = ((kc * 32 + hi * 8) * 2) ^ ((row & 7) << 4);
        a[i] = *(const bf16x8*)((const char*)sA + row * 128 + boff);
      }
#pragma unroll
      for (int i = 0; i < 4; ++i) {
        int row = wn * 64 + i * 16 + lo;
        int boff = ((kc * 32 + hi * 8) * 2) ^ ((row & 7) << 4);
        b[i] = *(const bf16x8*)((const char*)sB + row * 128 + boff);
      }
#pragma unroll
      for (int mi = 0; mi < 4; ++mi)
#pragma unroll
        for (int ni = 0; ni < 4; ++ni)
          acc[mi][ni] = MFMA16(a[mi], b[ni], acc[mi][ni]);
    }
  }
#pragma unroll
  for (int mi = 0; mi < 4; ++mi)
#pragma unroll
    for (int r = 0; r < 4; ++r) {
      size_t row = m0 + wm * 64 + mi * 16 + hi * 4 + r;
#pragma unroll
      for (int ni = 0; ni < 4; ++ni) {
        int col = n0 + wn * 64 + ni * 16 + lo;
        float v = acc[mi][ni][r] * osc;
        if constexpr (std::is_same<OutT, float>::value)
          C[row * N + col] = v;
        else
          C[row * N + col] = f32_to_bf16(v);
      }
    }
}

// ---------- causal flash attention (XCD-pinned + balanced CU pairing) -------
// Q,K: [tok 4096][feat 2048]; VT: [feat 2048][tok 4096].
// 512 blocks, ALL co-resident (2/CU). xcd = lin&7 pins each (b,h) group's
// K/V stream to one XCD L2 (FETCH 110->25 MB, verified R15). Blocks lin and
// lin+256 share a CU (idx and idx+32 within an XCD): decode makes that pair
// the SAME group with qt-pair (x, 15-x) -> per-CU load constant 34 iters
// AND both resident blocks stream identical L2-cached K/V.
constexpr float RTHR2 = 11.5416f;   // defer-max threshold, log2 units (= 8 nats)

__global__ __launch_bounds__(256, 2) void attn_fwd(const u16* __restrict__ Q,
                                                   const u16* __restrict__ K,
                                                   const u16* __restrict__ VT,
                                                   u16* __restrict__ O) {
  __shared__ __align__(16) u16 sK[2][64 * 128];   // [kv 64][dh 128], swizzled
  __shared__ __align__(16) u16 sV[2][128 * 64];   // [dh 128][kv 64], swizzled

  // decode: xcd = lin&7; idx = lin>>3; group = xcd + 8*(idx&3);
  // qt16 = idx>>2; qt = qt16<8 ? qt16 : 23-qt16  (idx,idx+32 -> qt x,15-x)
  const int lin = blockIdx.x;
  const int idx = lin >> 3;
  const int g   = (lin & 7) + 8 * (idx & 3);       // group 0..31
  const int qt16 = idx >> 2;
  const int qt  = (qt16 < 8) ? qt16 : 23 - qt16;   // bijective, pair-balanced
  const int h = g & 15, b = g >> 4;

  const int tid = threadIdx.x;
  const int lane = tid & 63, wid = tid >> 6;
  const int l31 = lane & 31, hi5 = lane >> 5;

  const size_t baseQK = ((size_t)b * 2048) * 2048 + (size_t)h * 128;
  const size_t baseV  = ((size_t)h * 128) * 4096 + (size_t)b * 2048;
  const int q0 = qt * 128;
  const int qw = q0 + wid * 32;      // wave's first query row
  const int qg = qw + l31;           // this lane's query row
  const int nt = 2 * qt + 2;

  // Q B-fragments (pre-scaled by SM_SCALE*log2e in the Q GEMM)
  bf16x8 qf[8];
#pragma unroll
  for (int kc = 0; kc < 8; ++kc)
    qf[kc] = *(const bf16x8*)(Q + baseQK + (size_t)qg * 2048 + kc * 16 + hi5 * 8);

  f32x16 o[4] = {};                  // O^T: [dh block d*32 + rowpat][q=l31]
  float m = -INFINITY, ls = 0.f;

  auto stage = [&](int buf, int t) {
    const int kv = t * 64;
#pragma unroll
    for (int i = 0; i < 4; ++i) {    // K tile: 64 rows x 256B
      int e = i * 256 + tid;
      int r = e >> 4;
      int bc = ((e & 15) * 16) ^ ((r & 7) << 4);
      ld_lds16(K + baseQK + (size_t)(kv + r) * 2048 + (bc >> 1), &sK[buf][e * 8]);
    }
#pragma unroll
    for (int i = 0; i < 4; ++i) {    // VT tile: 128 rows x 128B
      int e = i * 256 + tid;
      int r = e >> 3;
      int bc = ((e & 7) * 16) ^ ((r & 7) << 4);
      ld_lds16(VT + baseV + (size_t)r * 4096 + kv + (bc >> 1), &sV[buf][e * 8]);
    }
  };

  stage(0, 0);

  for (int t = 0; t < nt; ++t) {
    __syncthreads();                 // stage(t) complete; prev readers done
    if (t + 1 < nt) stage((t + 1) & 1, t + 1);
    const int kv0 = t * 64;
    if (kv0 > qw + 31) continue;     // beyond this wave's causal range
    const u16* bK = sK[t & 1];
    const u16* bV = sV[t & 1];

    // ---- S = K * Q^T : lane holds S[key(j,hi5)+kb*32][q=l31] ----
    f32x16 s[2] = {};
#pragma unroll
    for (int kb = 0; kb < 2; ++kb) {
      int row = kb * 32 + l31;
      int rsw = (row & 7) << 4;
#pragma unroll
      for (int kc = 0; kc < 8; ++kc) {
        int bo = (kc * 32 + hi5 * 16) ^ rsw;
        bf16x8 kf = *(const bf16x8*)((const char*)bK + row * 256 + bo);
        s[kb] = MFMA32(kf, qf[kc], s[kb]);
      }
    }

    // ---- mask (diag tiles only) ----
    if (kv0 + 63 > qw) {
#pragma unroll
      for (int kb = 0; kb < 2; ++kb)
#pragma unroll
        for (int j = 0; j < 16; ++j) {
          int keyg = kv0 + kb * 32 + (j & 3) + 8 * (j >> 2) + 4 * hi5;
          s[kb][j] = (keyg > qg) ? -3e38f : s[kb][j];
        }
    }

    // ---- row max: in-lane + cross-half shfl ----
    float pmax = -3e38f;
#pragma unroll
    for (int kb = 0; kb < 2; ++kb)
#pragma unroll
      for (int j = 0; j < 16; ++j) pmax = fmaxf(pmax, s[kb][j]);
    pmax = fmaxf(pmax, __shfl_xor(pmax, 32));

    // ---- defer-max rescale (log2 units) ----
    if (!__all(pmax - m <= RTHR2)) {
      float mn = fmaxf(m, pmax);
      float fr = exp2f(m - mn);
      ls *= fr;
#pragma unroll
      for (int d = 0; d < 4; ++d) o[d] *= fr;
      m = mn;
    }

    // ---- exp2 + row sum ----
    float rs = 0.f;
#pragma unroll
    for (int kb = 0; kb < 2; ++kb)
#pragma unroll
      for (int j = 0; j < 16; ++j) {
        float pv = exp2f(s[kb][j] - m);
        s[kb][j] = pv;
        rs += pv;
      }
    rs += __shfl_xor(rs, 32);
    ls += rs;

    // ---- pack P to bf16 pairs, redistribute into PV B-frags ----
    union PF { u32 w[4]; bf16x8 v; };
    PF pf[4];
#pragma unroll
    for (int kb = 0; kb < 2; ++kb)
#pragma unroll
      for (int gp = 0; gp < 2; ++gp) {
        u32 keep[2], send[2];
#pragma unroll
        for (int w = 0; w < 2; ++w) {
          int ja = 8 * gp + 2 * w;
          int jb = 8 * gp + 4 + 2 * w;
          u32 aa = pack2(s[kb][ja], s[kb][ja + 1]);
          u32 bb = pack2(s[kb][jb], s[kb][jb + 1]);
          keep[w] = hi5 ? bb : aa;
          send[w] = hi5 ? aa : bb;
        }
        u32 recv0 = (u32)__shfl_xor((int)send[0], 32);
        u32 recv1 = (u32)__shfl_xor((int)send[1], 32);
        PF& f = pf[2 * kb + gp];
        f.w[0] = hi5 ? recv0 : keep[0];
        f.w[1] = hi5 ? recv1 : keep[1];
        f.w[2] = hi5 ? keep[0] : recv0;
        f.w[3] = hi5 ? keep[1] : recv1;
      }

    // ---- O^T += V^T * P ----
#pragma unroll
    for (int d = 0; d < 4; ++d) {
      int row = d * 32 + l31;
      int rsw = (row & 7) << 4;
#pragma unroll
      for (int ks = 0; ks < 4; ++ks) {
        int bo = (ks * 32 + hi5 * 16) ^ rsw;
        bf16x8 vf = *(const bf16x8*)((const char*)bV + row * 128 + bo);
        o[d] = MFMA32(vf, pf[ks].v, o[d]);
      }
    }
  }

  // ---- normalize + store: O[tok][feat] ----
  float inv = 1.f / ls;
  size_t orow = (size_t)b * 2048 + qg;
#pragma unroll
  for (int d = 0; d < 4; ++d)
#pragma unroll
    for (int G = 0; G < 4; ++G) {
      union { u32 u[2]; ushort4 s4; } st;
      st.u[0] = pack2(o[d][4 * G + 0] * inv, o[d][4 * G + 1] * inv);
      st.u[1] = pack2(o[d][4 * G + 2] * inv, o[d][4 * G + 3] * inv);
      int col = h * 128 + d * 32 + 8 * G + 4 * hi5;
      *(ushort4*)(O + orow * 2048 + col) = st.s4;
    }
}

// ---------- launch ----------
extern "C" void kernel_launch(void* const* d_in, const int* in_sizes, int n_in,
                              void* d_out, int out_size, void* d_ws, size_t ws_size,
                              hipStream_t stream) {
  const float* x  = (const float*)d_in[0];
  const float* Wq = (const float*)d_in[1];
  const float* Wk = (const float*)d_in[2];
  const float* Wv = (const float*)d_in[3];
  const float* Wo = (const float*)d_in[4];
  float* out = (float*)d_out;

  constexpr int B = 2, S = 2048, D = 2048;
  constexpr int M = B * S;  // 4096
  // SM_SCALE * log2(e) — folded into the Q projection epilogue
  constexpr float QSC = 0.12751742f;

  char* ws = (char*)d_ws;
  u16* xb  = (u16*)ws; ws += (size_t)M * D * 2;
  u16* wqb = (u16*)ws; ws += (size_t)D * D * 2;   // wqb||wkb contiguous ->
  u16* wkb = (u16*)ws; ws += (size_t)D * D * 2;   // fused [4096][2048] B matrix
  u16* wvb = (u16*)ws; ws += (size_t)D * D * 2;
  u16* wob = (u16*)ws; ws += (size_t)D * D * 2;
  u16* q   = (u16*)ws; ws += (size_t)M * D * 2;   // [tok 4096][2048]
  u16* k   = (u16*)ws; ws += (size_t)M * D * 2;   // [tok 4096][2048]
  u16* vT  = (u16*)ws; ws += (size_t)M * D * 2;   // [feat 2048][tok 4096]
  u16* att = (u16*)ws; ws += (size_t)M * D * 2;

  cast_all<<<24576, 256, 0, stream>>>(x, Wq, Wk, Wv, Wo, xb, wqb, wkb, wvb, wob);

  // fused Q|K projection (de-fused outputs): cols<2048 -> q (scaled), else -> k
  gemm_nt256<u16><<<256, 512, 0, stream>>>(xb, wqb, q, k, M, 2 * D, D, D,
                                           QSC, 1.0f, D, 16);
  // V^T = Wv * x^T : output [feature][token] — free transpose for attention
  gemm_nt<u16><<<dim3(M / 128, D / 128), 256, 0, stream>>>(wvb, xb, vT, D, M, D, 1.0f);

  // XCD-pinned, CU-pair-balanced linear grid (512 blocks, all co-resident)
  attn_fwd<<<512, 256, 0, stream>>>(q, k, vT, att);

  gemm_nt<float><<<dim3(16, 32), 256, 0, stream>>>(att, wob, out, M, D, D, 1.0f);
}